// Round 1
// baseline (654.135 us; speedup 1.0000x reference)
//
#include <hip/hip_runtime.h>

#define NN 1024
#define BB 32
#define DD 128
#define EPSF 1e-6f
#define CAP 16384

typedef __bf16 bf16x8 __attribute__((ext_vector_type(8)));
typedef float  f32x4  __attribute__((ext_vector_type(4)));

__device__ __forceinline__ float bf2f(unsigned short u) {
  union { unsigned int i; float f; } v; v.i = ((unsigned int)u) << 16; return v.f;
}
__device__ __forceinline__ unsigned short f2bf(float f) {
  union { float f; unsigned int i; } v; v.f = f;
  unsigned int r = v.i + 0x7fffu + ((v.i >> 16) & 1u);
  return (unsigned short)(r >> 16);
}

// ---------------- convert / transpose kernels ----------------

// adj_weight f32 [B,N,N] -> Wp bf16 [B,N,N] and WpT bf16 [B,N,N] (WpT[b,i,k]=Wp[b,k,i])
__global__ __launch_bounds__(256) void convert_wp(const float* __restrict__ src,
    unsigned short* __restrict__ Wp, unsigned short* __restrict__ WpT) {
  __shared__ float tile[32][33];
  const int b = blockIdx.z;
  const int c0 = blockIdx.x * 32, r0 = blockIdx.y * 32;
  const int tx = threadIdx.x, ty = threadIdx.y;
  const size_t base = (size_t)b * NN * NN;
#pragma unroll
  for (int s = 0; s < 4; ++s) {
    int rr = ty + s * 8;
    float v = src[base + (size_t)(r0 + rr) * NN + c0 + tx];
    Wp[base + (size_t)(r0 + rr) * NN + c0 + tx] = f2bf(v);
    tile[rr][tx] = v;
  }
  __syncthreads();
#pragma unroll
  for (int s = 0; s < 4; ++s) {
    int rr = ty + s * 8;
    WpT[base + (size_t)(c0 + rr) * NN + r0 + tx] = f2bf(tile[tx][rr]);
  }
}

// x f32 [B,N,D] -> xT bf16 [B,D,N]
__global__ __launch_bounds__(256) void convert_x(const float* __restrict__ x,
    unsigned short* __restrict__ xT) {
  __shared__ float tile[32][33];
  const int b = blockIdx.z;
  const int d0 = blockIdx.x * 32, n0 = blockIdx.y * 32;
  const int tx = threadIdx.x, ty = threadIdx.y;
#pragma unroll
  for (int s = 0; s < 4; ++s) {
    int rr = ty + s * 8;
    tile[rr][tx] = x[(size_t)b * NN * DD + (size_t)(n0 + rr) * DD + d0 + tx];
  }
  __syncthreads();
#pragma unroll
  for (int s = 0; s < 4; ++s) {
    int rr = ty + s * 8;
    xT[(size_t)b * DD * NN + (size_t)(d0 + rr) * NN + n0 + tx] = f2bf(tile[tx][rr]);
  }
}

// mcode[i*N+j] bit0 = (adj[j,i]==1.0)
__global__ __launch_bounds__(256) void mask0_kernel(const float* __restrict__ adj,
    unsigned char* __restrict__ mcode) {
  __shared__ float tile[32][33];
  const int i0 = blockIdx.x * 32, j0 = blockIdx.y * 32;
  const int tx = threadIdx.x, ty = threadIdx.y;
#pragma unroll
  for (int s = 0; s < 4; ++s) {
    int rr = ty + s * 8;
    tile[rr][tx] = adj[(size_t)(j0 + rr) * NN + i0 + tx];
  }
  __syncthreads();
#pragma unroll
  for (int s = 0; s < 4; ++s) {
    int rr = ty + s * 8;
    mcode[(size_t)(i0 + rr) * NN + j0 + tx] = (tile[tx][rr] == 1.0f) ? 1 : 0;
  }
}

// ---------------- exact f32 square: C = A @ A (1024x1024) ----------------
// mode 0: store C (=A^2) and OR bit1 of mcode at transposed index where C==1
// mode 1: (A^4 pass) record entries (j<<16|i) where C==1 into entries[], count in nnz
__global__ __launch_bounds__(256) void sq_f32(const float* __restrict__ A, float* __restrict__ C,
    unsigned char* __restrict__ mcode, unsigned int* __restrict__ entries,
    int* __restrict__ nnz, int mode) {
  __shared__ float As[64][17];
  __shared__ float Bs[16][65];
  const int m0 = blockIdx.y * 64, n0 = blockIdx.x * 64;
  const int tid = threadIdx.x, tx = tid & 15, ty = tid >> 4;
  float c[4][4] = {{0.f}};
  for (int k0 = 0; k0 < NN; k0 += 16) {
#pragma unroll
    for (int i = 0; i < 4; ++i) {
      int e = tid + i * 256;
      As[e >> 4][e & 15] = A[(size_t)(m0 + (e >> 4)) * NN + k0 + (e & 15)];
      Bs[e >> 6][e & 63] = A[(size_t)(k0 + (e >> 6)) * NN + n0 + (e & 63)];
    }
    __syncthreads();
#pragma unroll
    for (int kk = 0; kk < 16; ++kk) {
      float a[4], bv[4];
#pragma unroll
      for (int m = 0; m < 4; ++m) a[m] = As[ty + m * 16][kk];
#pragma unroll
      for (int n = 0; n < 4; ++n) bv[n] = Bs[kk][tx + n * 16];
#pragma unroll
      for (int m = 0; m < 4; ++m)
#pragma unroll
        for (int n = 0; n < 4; ++n) c[m][n] += a[m] * bv[n];
    }
    __syncthreads();
  }
#pragma unroll
  for (int m = 0; m < 4; ++m)
    for (int n = 0; n < 4; ++n) {
      int row = m0 + ty + m * 16, col = n0 + tx + n * 16;
      float v = c[m][n];
      if (mode == 0) {
        C[(size_t)row * NN + col] = v;
        if (v == 1.0f) mcode[(size_t)col * NN + row] |= 2;
      } else {
        if (v == 1.0f) {
          int idx = atomicAdd(nnz, 1);
          if (idx < CAP) entries[idx] = ((unsigned)row << 16) | (unsigned)col;
        }
      }
    }
}

// ---------------- MFMA bf16 GEMM: C[m,n] = sum_k A[m,k] * B[n,k] ----------------
#define BM 128
#define BN 128
#define BK 32

__device__ __forceinline__ void async_cp16(const void* g, void* l) {
  __builtin_amdgcn_global_load_lds((const __attribute__((address_space(1))) void*)g,
                                   (__attribute__((address_space(3))) void*)l, 16, 0, 0);
}

struct EpiWcomb {
  const unsigned short* WpT;
  const unsigned char* mcode;
  unsigned short* out;
  __device__ __forceinline__ void operator()(int b, int i, int j, float v) const {
    size_t bnn = (size_t)b * (size_t)NN * NN;
    size_t idx = (size_t)i * NN + j;
    unsigned char mc = mcode[idx];
    float r = (mc & 2) ? v : 0.f;
    if (mc & 1) r += bf2f(WpT[bnn + idx]);
    out[bnn + idx] = f2bf(r);
  }
};

struct EpiAgg {
  float* agg;
  __device__ __forceinline__ void operator()(int b, int i, int d, float v) const {
    agg[(size_t)b * NN * DD + (size_t)i * DD + d] = v;
  }
};

template <typename Epi>
__global__ __launch_bounds__(256) void gemm_bt(const unsigned short* __restrict__ Abase,
    const unsigned short* __restrict__ Bbase, size_t sA, size_t sB, Epi epi) {
  __shared__ __align__(16) unsigned short As[BM * BK];
  __shared__ __align__(16) unsigned short Bs[BN * BK];
  const int b = blockIdx.z;
  const int tm = blockIdx.x * BM;
  const int tn = blockIdx.y * BN;
  const unsigned short* A = Abase + (size_t)b * sA;
  const unsigned short* B = Bbase + (size_t)b * sB;
  const int tid = threadIdx.x;
  const int w = tid >> 6, l = tid & 63;
  const int lr = l >> 2, lc = l & 3;          // staging: row-within-issue, 16B chunk slot
  const int fr = l & 15, quad = l >> 4;       // fragment: row, k-quad
  const int moff = (w & 1) * 64, noff = (w >> 1) * 64;
  f32x4 acc[4][4];
#pragma unroll
  for (int mi = 0; mi < 4; ++mi)
#pragma unroll
    for (int ni = 0; ni < 4; ++ni) acc[mi][ni] = (f32x4){0.f, 0.f, 0.f, 0.f};

  for (int k0 = 0; k0 < NN; k0 += BK) {
    // stage A and B tiles: global_load_lds width 16; XOR-swizzled k-chunk so that
    // fragment ds_read_b128 is bank-conflict-free while LDS stays lane-contiguous.
#pragma unroll
    for (int s = 0; s < 2; ++s) {
      const int rbase = (w + s * 4) * 16;
      int r = rbase + lr;
      int kc = lc ^ ((r >> 1) & 3);
      async_cp16(A + (size_t)(tm + r) * NN + k0 + kc * 8, (void*)(As + rbase * BK));
      async_cp16(B + (size_t)(tn + r) * NN + k0 + kc * 8, (void*)(Bs + rbase * BK));
    }
    __syncthreads();
    bf16x8 af[4], bfr[4];
#pragma unroll
    for (int mi = 0; mi < 4; ++mi) {
      int r = moff + mi * 16 + fr;
      int kc = quad ^ ((r >> 1) & 3);
      af[mi] = *(const bf16x8*)(As + r * BK + kc * 8);
    }
#pragma unroll
    for (int ni = 0; ni < 4; ++ni) {
      int r = noff + ni * 16 + fr;
      int kc = quad ^ ((r >> 1) & 3);
      bfr[ni] = *(const bf16x8*)(Bs + r * BK + kc * 8);
    }
#pragma unroll
    for (int mi = 0; mi < 4; ++mi)
#pragma unroll
      for (int ni = 0; ni < 4; ++ni)
        acc[mi][ni] = __builtin_amdgcn_mfma_f32_16x16x32_bf16(af[mi], bfr[ni], acc[mi][ni], 0, 0, 0);
    __syncthreads();
  }
  // C/D layout: col = lane&15, row = quad*4 + reg
#pragma unroll
  for (int mi = 0; mi < 4; ++mi)
#pragma unroll
    for (int ni = 0; ni < 4; ++ni)
#pragma unroll
      for (int t = 0; t < 4; ++t)
        epi(b, tm + moff + mi * 16 + quad * 4 + t, tn + noff + ni * 16 + fr, acc[mi][ni][t]);
}

// ---------------- gated hop-2 sparse fixup (expected: nnz==0, exits) ----------------
__global__ __launch_bounds__(256) void hop2_fix(const unsigned short* __restrict__ Wp,
    const unsigned short* __restrict__ WpT, const int* __restrict__ nnz,
    const unsigned int* __restrict__ entries, unsigned short* __restrict__ WcombT) {
  int n = *nnz;
  if (n > CAP) n = CAP;
  if (n == 0) return;
  __shared__ float rbuf[256];
  const int b = blockIdx.x;
  const size_t bnn = (size_t)b * NN * NN;
  for (int e = blockIdx.y; e < n; e += gridDim.y) {
    unsigned int ent = entries[e];
    int j = ent >> 16, i = ent & 0xFFFF;
    float s = 0.f;
    for (int k = threadIdx.x; k < NN; k += 256) {
      float u = 0.f, v = 0.f;
      const unsigned short* wj  = Wp  + bnn + (size_t)j * NN;
      const unsigned short* wtk = WpT + bnn + (size_t)k * NN;
      const unsigned short* wk  = Wp  + bnn + (size_t)k * NN;
      const unsigned short* wti = WpT + bnn + (size_t)i * NN;
      for (int t = 0; t < NN; ++t) {
        u += bf2f(wj[t]) * bf2f(wtk[t]);
        v += bf2f(wk[t]) * bf2f(wti[t]);
      }
      s += u * v;
    }
    rbuf[threadIdx.x] = s;
    __syncthreads();
    for (int off = 128; off > 0; off >>= 1) {
      if (threadIdx.x < off) rbuf[threadIdx.x] += rbuf[threadIdx.x + off];
      __syncthreads();
    }
    if (threadIdx.x == 0) {
      size_t idx = bnn + (size_t)i * NN + j;
      WcombT[idx] = f2bf(bf2f(WcombT[idx]) + rbuf[0]);
    }
    __syncthreads();
  }
}

// ---------------- fused Linear + residual + LayerNorm ----------------
#define ROWS_PER_BLK 32
__global__ __launch_bounds__(256) void fused_out(const float* agg, const float* __restrict__ x,
    const float* __restrict__ W, const float* __restrict__ bias,
    const float* __restrict__ g2, const float* __restrict__ bsh, float* out) {
  __shared__ unsigned short Wl[128 * 136];  // stride 136: 16B-aligned rows, conflict-free b128 reads
  __shared__ float ar[256];
  __shared__ float xr[256];
  __shared__ float wred[8];
  const int tid = threadIdx.x;
  for (int e = tid; e < 16384; e += 256) Wl[(e >> 7) * 136 + (e & 127)] = f2bf(W[e]);
  const int half = tid >> 7, o = tid & 127;
  const int w = tid >> 6, lane = tid & 63;
  const float bo = bias[o], go = g2[o], b2o = bsh[o];
  const size_t row0 = (size_t)blockIdx.x * ROWS_PER_BLK;
  for (int rr = 0; rr < ROWS_PER_BLK; rr += 2) {
    const size_t rbase = (row0 + rr) * DD;
    __syncthreads();
    ar[tid] = agg[rbase + tid];
    xr[tid] = x[rbase + tid];
    __syncthreads();
    float hv = bo + xr[half * 128 + o];
    const unsigned short* wrow = &Wl[o * 136];
    const float* arow = &ar[half * 128];
#pragma unroll
    for (int d8 = 0; d8 < 16; ++d8) {
      bf16x8 wv = *(const bf16x8*)(wrow + d8 * 8);
#pragma unroll
      for (int t = 0; t < 8; ++t) hv += (float)wv[t] * arow[d8 * 8 + t];
    }
    float s = hv, q = hv * hv;
#pragma unroll
    for (int off = 32; off > 0; off >>= 1) {
      s += __shfl_xor(s, off);
      q += __shfl_xor(q, off);
    }
    if (lane == 0) { wred[w] = s; wred[4 + w] = q; }
    __syncthreads();
    float st = wred[half * 2] + wred[half * 2 + 1];
    float qt = wred[4 + half * 2] + wred[4 + half * 2 + 1];
    float mean = st * (1.0f / 128.0f);
    float var = (qt - 128.0f * mean * mean) * (1.0f / 127.0f);
    var = fmaxf(var, 0.0f);
    float stdv = sqrtf(var);
    out[rbase + tid] = go * (hv - mean) / (stdv + EPSF) + b2o;
  }
}

// ---------------- launch ----------------
extern "C" void kernel_launch(void* const* d_in, const int* in_sizes, int n_in,
                              void* d_out, int out_size, void* d_ws, size_t ws_size,
                              hipStream_t stream) {
  (void)in_sizes; (void)n_in; (void)out_size; (void)ws_size;
  const float* x    = (const float*)d_in[0];
  const float* adjw = (const float*)d_in[1];
  const float* adj  = (const float*)d_in[2];
  const float* W    = (const float*)d_in[3];
  const float* bias = (const float*)d_in[4];
  const float* a2   = (const float*)d_in[5];
  const float* b2   = (const float*)d_in[6];
  float* out = (float*)d_out;

  char* ws = (char*)d_ws;
  unsigned short* Wp_bf  = (unsigned short*)(ws);                 // 64 MiB
  unsigned short* WpT_bf = (unsigned short*)(ws + 67108864);      // 64 MiB
  unsigned short* WcombT = (unsigned short*)(ws + 134217728);     // 64 MiB
  unsigned short* xT_bf  = (unsigned short*)(ws + 201326592);     // 8 MiB
  float* A2              = (float*)(ws + 209715200);              // 4 MiB
  unsigned char* mcode   = (unsigned char*)(ws + 213909504);      // 1 MiB
  unsigned int* entries  = (unsigned int*)(ws + 214958080);       // 64 KiB
  int* nnz2              = (int*)(ws + 215023616);                // 4 B
  float* agg = out;  // reuse d_out as agg scratch; fused_out reads then overwrites per-row

  hipMemsetAsync(nnz2, 0, 4, stream);

  dim3 blk32(32, 8, 1);
  convert_wp<<<dim3(32, 32, 32), blk32, 0, stream>>>(adjw, Wp_bf, WpT_bf);
  convert_x<<<dim3(4, 32, 32), blk32, 0, stream>>>(x, xT_bf);
  mask0_kernel<<<dim3(32, 32, 1), blk32, 0, stream>>>(adj, mcode);
  sq_f32<<<dim3(16, 16, 1), 256, 0, stream>>>(adj, A2, mcode, entries, nnz2, 0);
  sq_f32<<<dim3(16, 16, 1), 256, 0, stream>>>(A2, nullptr, nullptr, entries, nnz2, 1);

  EpiWcomb e1{WpT_bf, mcode, WcombT};
  gemm_bt<EpiWcomb><<<dim3(8, 8, 32), 256, 0, stream>>>(WpT_bf, Wp_bf,
      (size_t)NN * NN, (size_t)NN * NN, e1);

  hop2_fix<<<dim3(32, 64, 1), 256, 0, stream>>>(Wp_bf, WpT_bf, nnz2, entries, WcombT);

  EpiAgg e2{agg};
  gemm_bt<EpiAgg><<<dim3(8, 1, 32), 256, 0, stream>>>(WcombT, xT_bf,
      (size_t)NN * NN, (size_t)DD * NN, e2);

  fused_out<<<dim3(1024, 1, 1), 256, 0, stream>>>(agg, x, W, bias, a2, b2, out);
}

// Round 2
// 538.170 us; speedup vs baseline: 1.2155x; 1.2155x over previous
//
#include <hip/hip_runtime.h>

#define NN 1024
#define BB 32
#define DD 128
#define EPSF 1e-6f
#define CAP 16384

typedef __bf16 bf16x8 __attribute__((ext_vector_type(8)));
typedef float  f32x4  __attribute__((ext_vector_type(4)));
typedef unsigned short u16x8 __attribute__((ext_vector_type(8)));

__device__ __forceinline__ float bf2f(unsigned short u) {
  union { unsigned int i; float f; } v; v.i = ((unsigned int)u) << 16; return v.f;
}
__device__ __forceinline__ unsigned short f2bf(float f) {
  union { float f; unsigned int i; } v; v.f = f;
  unsigned int r = v.i + 0x7fffu + ((v.i >> 16) & 1u);
  return (unsigned short)(r >> 16);
}

// ---------------- convert / transpose kernels ----------------

// adj_weight f32 [B,N,N] -> Wp bf16 [B,N,N] and WpT bf16 (transposed), 16B ld/st.
__global__ __launch_bounds__(256) void convert_wp(const float* __restrict__ src,
    unsigned short* __restrict__ Wp, unsigned short* __restrict__ WpT) {
  __shared__ float tile[64][65];
  const int b = blockIdx.z;
  const int c0 = blockIdx.x * 64, r0 = blockIdx.y * 64;
  const int t = threadIdx.x;
  const int rr = t >> 3, cb = (t & 7) * 8;   // 32 rows/pass, 8 elems/thread
  const size_t base = (size_t)b * NN * NN;
#pragma unroll
  for (int p = 0; p < 2; ++p) {
    const int r = rr + p * 32;
    const float* srow = src + base + (size_t)(r0 + r) * NN + c0 + cb;
    f32x4 v0 = *(const f32x4*)srow;
    f32x4 v1 = *(const f32x4*)(srow + 4);
    u16x8 w;
#pragma unroll
    for (int j = 0; j < 4; ++j) { w[j] = f2bf(v0[j]); w[4 + j] = f2bf(v1[j]); }
    *(u16x8*)(Wp + base + (size_t)(r0 + r) * NN + c0 + cb) = w;
#pragma unroll
    for (int j = 0; j < 4; ++j) { tile[r][cb + j] = v0[j]; tile[r][cb + 4 + j] = v1[j]; }
  }
  __syncthreads();
#pragma unroll
  for (int p = 0; p < 2; ++p) {
    const int r = rr + p * 32;   // row of WpT tile = source column
    u16x8 w;
#pragma unroll
    for (int j = 0; j < 8; ++j) w[j] = f2bf(tile[cb + j][r]);
    *(u16x8*)(WpT + base + (size_t)(c0 + r) * NN + r0 + cb) = w;
  }
}

// x f32 [B,N,D] -> xT bf16 [B,D,N]
__global__ __launch_bounds__(256) void convert_x(const float* __restrict__ x,
    unsigned short* __restrict__ xT) {
  __shared__ float tile[32][33];
  const int b = blockIdx.z;
  const int d0 = blockIdx.x * 32, n0 = blockIdx.y * 32;
  const int tx = threadIdx.x, ty = threadIdx.y;
#pragma unroll
  for (int s = 0; s < 4; ++s) {
    int rr = ty + s * 8;
    tile[rr][tx] = x[(size_t)b * NN * DD + (size_t)(n0 + rr) * DD + d0 + tx];
  }
  __syncthreads();
#pragma unroll
  for (int s = 0; s < 4; ++s) {
    int rr = ty + s * 8;
    xT[(size_t)b * DD * NN + (size_t)(d0 + rr) * NN + n0 + tx] = f2bf(tile[tx][rr]);
  }
}

// adj -> mcode bit0 (= adj[j,i]==1 at [i,j]), adj_bf (copy), adjT_bf (transpose)
__global__ __launch_bounds__(256) void mask0cvt(const float* __restrict__ adj,
    unsigned char* __restrict__ mcode, unsigned short* __restrict__ adjbf,
    unsigned short* __restrict__ adjTbf) {
  __shared__ float tile[32][33];
  const int i0 = blockIdx.x * 32, j0 = blockIdx.y * 32;
  const int tx = threadIdx.x, ty = threadIdx.y;
#pragma unroll
  for (int s = 0; s < 4; ++s) {
    int rr = ty + s * 8;
    float v = adj[(size_t)(j0 + rr) * NN + i0 + tx];
    adjbf[(size_t)(j0 + rr) * NN + i0 + tx] = f2bf(v);
    tile[rr][tx] = v;
  }
  __syncthreads();
#pragma unroll
  for (int s = 0; s < 4; ++s) {
    int rr = ty + s * 8;
    float v = tile[tx][rr];
    adjTbf[(size_t)(i0 + rr) * NN + j0 + tx] = f2bf(v);
    mcode[(size_t)(i0 + rr) * NN + j0 + tx] = (v == 1.0f) ? 1 : 0;
  }
}

// ---------------- MFMA bf16 GEMM: C[m,n] = sum_k A[m,k] * B[n,k] ----------------
// 3-stage software-pipelined: triple LDS buffer, raw s_barrier + fine vmcnt so
// prefetched global_load_lds stays in flight across barriers.
#define BM 128
#define BN 128
#define BK 32
#define NIT (NN / BK)

__device__ __forceinline__ void async_cp16(const void* g, void* l) {
  __builtin_amdgcn_global_load_lds((const __attribute__((address_space(1))) void*)g,
                                   (__attribute__((address_space(3))) void*)l, 16, 0, 0);
}

struct EpiWcomb {
  const unsigned short* WpT;
  const unsigned char* mcode;
  unsigned short* out;
  __device__ __forceinline__ void operator()(int b, int i, int j, float v) const {
    size_t bnn = (size_t)b * (size_t)NN * NN;
    size_t idx = (size_t)i * NN + j;
    unsigned char mc = mcode[idx];
    float r = (mc & 2) ? v : 0.f;
    if (mc & 1) r += bf2f(WpT[bnn + idx]);
    out[bnn + idx] = f2bf(r);
  }
};

struct EpiAgg {
  float* agg;
  __device__ __forceinline__ void operator()(int b, int i, int d, float v) const {
    agg[(size_t)b * NN * DD + (size_t)i * DD + d] = v;
  }
};

// A^2 epilogue: exact small ints; store bf16 A2 + A2T, set mask bit1 at transposed idx
struct EpiSq1 {
  unsigned short* A2;
  unsigned short* A2T;
  unsigned char* mcode;
  __device__ __forceinline__ void operator()(int b, int m, int n, float v) const {
    unsigned short bv = f2bf(v);
    A2[(size_t)m * NN + n] = bv;
    A2T[(size_t)n * NN + m] = bv;
    if (v == 1.0f) mcode[(size_t)n * NN + m] |= 2;
  }
};

// A^4 epilogue: record ==1.0 entries (exact integer arithmetic)
struct EpiSq2 {
  unsigned int* entries;
  int* nnz;
  __device__ __forceinline__ void operator()(int b, int m, int n, float v) const {
    if (v == 1.0f) {
      int idx = atomicAdd(nnz, 1);
      if (idx < CAP) entries[idx] = ((unsigned)m << 16) | (unsigned)n;
    }
  }
};

template <typename Epi>
__global__ __launch_bounds__(256) void gemm_bt(const unsigned short* __restrict__ Abase,
    const unsigned short* __restrict__ Bbase, size_t sA, size_t sB, int swz, Epi epi) {
  __shared__ __align__(16) unsigned short As[3 * BM * BK];
  __shared__ __align__(16) unsigned short Bs[3 * BN * BK];
  const int b = blockIdx.z;
  int bx = blockIdx.x, by = blockIdx.y;
  if (swz) {  // 2x4 rect per XCD (dispatch%8 heuristic) for L2 locality
    int lin = bx + (by << 3);
    int r = lin & 7, s = lin >> 3;
    bx = ((r & 3) << 1) | (s & 1);
    by = ((r >> 2) << 2) | (s >> 1);
  }
  const int tm = bx * BM;
  const int tn = by * BN;
  const unsigned short* A = Abase + (size_t)b * sA;
  const unsigned short* B = Bbase + (size_t)b * sB;
  const int tid = threadIdx.x;
  const int w = tid >> 6, l = tid & 63;
  const int lr = l >> 2, lc = l & 3;          // staging: row-within-issue, 16B chunk slot
  const int fr = l & 15, quad = l >> 4;       // fragment: row, k-quad
  const int moff = (w & 1) * 64, noff = (w >> 1) * 64;
  f32x4 acc[4][4];
#pragma unroll
  for (int mi = 0; mi < 4; ++mi)
#pragma unroll
    for (int ni = 0; ni < 4; ++ni) acc[mi][ni] = (f32x4){0.f, 0.f, 0.f, 0.f};

  auto issue = [&](int kt, int buf) {
    unsigned short* Ad = As + buf * (BM * BK);
    unsigned short* Bd = Bs + buf * (BN * BK);
#pragma unroll
    for (int s = 0; s < 2; ++s) {
      const int rb = (w + s * 4) * 16;
      int r = rb + lr;
      int kc = lc ^ ((r >> 1) & 3);  // XOR swizzle: conflict-free frag reads
      async_cp16(A + (size_t)(tm + r) * NN + kt * BK + kc * 8, (void*)(Ad + rb * BK));
      async_cp16(B + (size_t)(tn + r) * NN + kt * BK + kc * 8, (void*)(Bd + rb * BK));
    }
  };
  auto compute = [&](int buf) {
    const unsigned short* Ab = As + buf * (BM * BK);
    const unsigned short* Bb = Bs + buf * (BN * BK);
    bf16x8 af[4], bfr[4];
#pragma unroll
    for (int mi = 0; mi < 4; ++mi) {
      int r = moff + mi * 16 + fr;
      int kc = quad ^ ((r >> 1) & 3);
      af[mi] = *(const bf16x8*)(Ab + r * BK + kc * 8);
    }
#pragma unroll
    for (int ni = 0; ni < 4; ++ni) {
      int r = noff + ni * 16 + fr;
      int kc = quad ^ ((r >> 1) & 3);
      bfr[ni] = *(const bf16x8*)(Bb + r * BK + kc * 8);
    }
#pragma unroll
    for (int mi = 0; mi < 4; ++mi)
#pragma unroll
      for (int ni = 0; ni < 4; ++ni)
        acc[mi][ni] = __builtin_amdgcn_mfma_f32_16x16x32_bf16(af[mi], bfr[ni], acc[mi][ni], 0, 0, 0);
  };

  // prologue: 3 tiles in flight (12 loads/lane)
  issue(0, 0); issue(1, 1); issue(2, 2);
#pragma unroll 1
  for (int kt = 0; kt < NIT - 3; ++kt) {
    asm volatile("s_waitcnt vmcnt(8)" ::: "memory");  // tile kt drained; kt+1,kt+2 in flight
    __builtin_amdgcn_s_barrier();
    asm volatile("" ::: "memory");
    compute(kt % 3);
    asm volatile("" ::: "memory");
    __builtin_amdgcn_s_barrier();                     // all waves done reading buf kt%3
    asm volatile("" ::: "memory");
    issue(kt + 3, kt % 3);
  }
  asm volatile("s_waitcnt vmcnt(8)" ::: "memory");    // kt = NIT-3
  __builtin_amdgcn_s_barrier();
  asm volatile("" ::: "memory");
  compute((NIT - 3) % 3);
  asm volatile("s_waitcnt vmcnt(4)" ::: "memory");    // kt = NIT-2
  __builtin_amdgcn_s_barrier();
  asm volatile("" ::: "memory");
  compute((NIT - 2) % 3);
  asm volatile("s_waitcnt vmcnt(0)" ::: "memory");    // kt = NIT-1
  __builtin_amdgcn_s_barrier();
  asm volatile("" ::: "memory");
  compute((NIT - 1) % 3);
  asm volatile("" ::: "memory");

  // C/D layout: col = lane&15, row = quad*4 + reg
#pragma unroll
  for (int mi = 0; mi < 4; ++mi)
#pragma unroll
    for (int ni = 0; ni < 4; ++ni)
#pragma unroll
      for (int t = 0; t < 4; ++t)
        epi(b, tm + moff + mi * 16 + quad * 4 + t, tn + noff + ni * 16 + fr, acc[mi][ni][t]);
}

// ---------------- gated hop-2 sparse fixup (expected: nnz==0, exits) ----------------
__global__ __launch_bounds__(256) void hop2_fix(const unsigned short* __restrict__ Wp,
    const unsigned short* __restrict__ WpT, const int* __restrict__ nnz,
    const unsigned int* __restrict__ entries, unsigned short* __restrict__ WcombT) {
  int n = *nnz;
  if (n > CAP) n = CAP;
  if (n == 0) return;
  __shared__ float rbuf[256];
  const int b = blockIdx.x;
  const size_t bnn = (size_t)b * NN * NN;
  for (int e = blockIdx.y; e < n; e += gridDim.y) {
    unsigned int ent = entries[e];
    int j = ent >> 16, i = ent & 0xFFFF;
    float s = 0.f;
    for (int k = threadIdx.x; k < NN; k += 256) {
      float u = 0.f, v = 0.f;
      const unsigned short* wj  = Wp  + bnn + (size_t)j * NN;
      const unsigned short* wtk = WpT + bnn + (size_t)k * NN;
      const unsigned short* wk  = Wp  + bnn + (size_t)k * NN;
      const unsigned short* wti = WpT + bnn + (size_t)i * NN;
      for (int t = 0; t < NN; ++t) {
        u += bf2f(wj[t]) * bf2f(wtk[t]);
        v += bf2f(wk[t]) * bf2f(wti[t]);
      }
      s += u * v;
    }
    rbuf[threadIdx.x] = s;
    __syncthreads();
    for (int off = 128; off > 0; off >>= 1) {
      if (threadIdx.x < off) rbuf[threadIdx.x] += rbuf[threadIdx.x + off];
      __syncthreads();
    }
    if (threadIdx.x == 0) {
      size_t idx = bnn + (size_t)i * NN + j;
      WcombT[idx] = f2bf(bf2f(WcombT[idx]) + rbuf[0]);
    }
    __syncthreads();
  }
}

// ---------------- fused Linear + residual + LayerNorm ----------------
#define ROWS_PER_BLK 32
__global__ __launch_bounds__(256) void fused_out(const float* agg, const float* __restrict__ x,
    const float* __restrict__ W, const float* __restrict__ bias,
    const float* __restrict__ g2, const float* __restrict__ bsh, float* out) {
  __shared__ unsigned short Wl[128 * 136];
  __shared__ float ar[256];
  __shared__ float xr[256];
  __shared__ float wred[8];
  const int tid = threadIdx.x;
  for (int e = tid; e < 16384; e += 256) Wl[(e >> 7) * 136 + (e & 127)] = f2bf(W[e]);
  const int half = tid >> 7, o = tid & 127;
  const int w = tid >> 6, lane = tid & 63;
  const float bo = bias[o], go = g2[o], b2o = bsh[o];
  const size_t row0 = (size_t)blockIdx.x * ROWS_PER_BLK;
  for (int rr = 0; rr < ROWS_PER_BLK; rr += 2) {
    const size_t rbase = (row0 + rr) * DD;
    __syncthreads();
    ar[tid] = agg[rbase + tid];
    xr[tid] = x[rbase + tid];
    __syncthreads();
    float hv = bo + xr[half * 128 + o];
    const unsigned short* wrow = &Wl[o * 136];
    const float* arow = &ar[half * 128];
#pragma unroll
    for (int d8 = 0; d8 < 16; ++d8) {
      bf16x8 wv = *(const bf16x8*)(wrow + d8 * 8);
#pragma unroll
      for (int t = 0; t < 8; ++t) hv += (float)wv[t] * arow[d8 * 8 + t];
    }
    float s = hv, q = hv * hv;
#pragma unroll
    for (int off = 32; off > 0; off >>= 1) {
      s += __shfl_xor(s, off);
      q += __shfl_xor(q, off);
    }
    if (lane == 0) { wred[w] = s; wred[4 + w] = q; }
    __syncthreads();
    float st = wred[half * 2] + wred[half * 2 + 1];
    float qt = wred[4 + half * 2] + wred[4 + half * 2 + 1];
    float mean = st * (1.0f / 128.0f);
    float var = (qt - 128.0f * mean * mean) * (1.0f / 127.0f);
    var = fmaxf(var, 0.0f);
    float stdv = sqrtf(var);
    out[rbase + tid] = go * (hv - mean) / (stdv + EPSF) + b2o;
  }
}

// ---------------- launch ----------------
extern "C" void kernel_launch(void* const* d_in, const int* in_sizes, int n_in,
                              void* d_out, int out_size, void* d_ws, size_t ws_size,
                              hipStream_t stream) {
  (void)in_sizes; (void)n_in; (void)out_size; (void)ws_size;
  const float* x    = (const float*)d_in[0];
  const float* adjw = (const float*)d_in[1];
  const float* adj  = (const float*)d_in[2];
  const float* W    = (const float*)d_in[3];
  const float* bias = (const float*)d_in[4];
  const float* a2   = (const float*)d_in[5];
  const float* b2   = (const float*)d_in[6];
  float* out = (float*)d_out;

  char* ws = (char*)d_ws;
  unsigned short* Wp_bf   = (unsigned short*)(ws);                 // 64 MiB
  unsigned short* WpT_bf  = (unsigned short*)(ws + 67108864);      // 64 MiB
  unsigned short* WcombT  = (unsigned short*)(ws + 134217728);     // 64 MiB
  unsigned short* xT_bf   = (unsigned short*)(ws + 201326592);     // 8 MiB
  unsigned short* adj_bf  = (unsigned short*)(ws + 209715200);     // 2 MiB
  unsigned short* adjT_bf = (unsigned short*)(ws + 211812352);     // 2 MiB
  unsigned short* A2_bf   = (unsigned short*)(ws + 213909504);     // 2 MiB
  unsigned short* A2T_bf  = (unsigned short*)(ws + 216006656);     // 2 MiB
  unsigned char* mcode    = (unsigned char*)(ws + 218103808);      // 1 MiB
  unsigned int* entries   = (unsigned int*)(ws + 219152384);       // 64 KiB
  int* nnz2               = (int*)(ws + 219217920);                // 4 B
  float* agg = out;  // d_out doubles as agg scratch

  hipMemsetAsync(nnz2, 0, 4, stream);

  dim3 blk32(32, 8, 1);
  convert_wp<<<dim3(16, 16, 32), 256, 0, stream>>>(adjw, Wp_bf, WpT_bf);
  convert_x<<<dim3(4, 32, 32), blk32, 0, stream>>>(x, xT_bf);
  mask0cvt<<<dim3(32, 32, 1), blk32, 0, stream>>>(adj, mcode, adj_bf, adjT_bf);

  // A^2 via exact bf16 MFMA (0/1 inputs, integer sums < 2^24)
  EpiSq1 es1{A2_bf, A2T_bf, mcode};
  gemm_bt<EpiSq1><<<dim3(8, 8, 1), 256, 0, stream>>>(adj_bf, adjT_bf, 0, 0, 1, es1);
  // A^4 via exact bf16 MFMA (A^2 ints < 256 exact in bf16)
  EpiSq2 es2{entries, nnz2};
  gemm_bt<EpiSq2><<<dim3(8, 8, 1), 256, 0, stream>>>(A2_bf, A2T_bf, 0, 0, 1, es2);

  EpiWcomb e1{WpT_bf, mcode, WcombT};
  gemm_bt<EpiWcomb><<<dim3(8, 8, 32), 256, 0, stream>>>(WpT_bf, Wp_bf,
      (size_t)NN * NN, (size_t)NN * NN, 1, e1);

  hop2_fix<<<dim3(32, 8, 1), 256, 0, stream>>>(Wp_bf, WpT_bf, nnz2, entries, WcombT);

  EpiAgg e2{agg};
  gemm_bt<EpiAgg><<<dim3(8, 1, 32), 256, 0, stream>>>(WcombT, xT_bf,
      (size_t)NN * NN, (size_t)DD * NN, 0, e2);

  fused_out<<<dim3(1024, 1, 1), 256, 0, stream>>>(agg, x, W, bias, a2, b2, out);
}

// Round 3
// 520.757 us; speedup vs baseline: 1.2561x; 1.0334x over previous
//
#include <hip/hip_runtime.h>

#define NN 1024
#define BB 32
#define DD 128
#define EPSF 1e-6f
#define CAP 16384
#define NNNN ((size_t)NN * NN)

typedef __bf16 bf16x8 __attribute__((ext_vector_type(8)));
typedef float  f32x4  __attribute__((ext_vector_type(4)));
typedef unsigned short u16x8 __attribute__((ext_vector_type(8)));

__device__ __forceinline__ float bf2f(unsigned short u) {
  union { unsigned int i; float f; } v; v.i = ((unsigned int)u) << 16; return v.f;
}
__device__ __forceinline__ unsigned short f2bf(float f) {
  union { float f; unsigned int i; } v; v.f = f;
  unsigned int r = v.i + 0x7fffu + ((v.i >> 16) & 1u);
  return (unsigned short)(r >> 16);
}

// ---------------- convert / transpose kernels ----------------

__global__ __launch_bounds__(256) void convert_wp(const float* __restrict__ src,
    unsigned short* __restrict__ Wp, unsigned short* __restrict__ WpT) {
  __shared__ float tile[64][65];
  const int b = blockIdx.z;
  const int c0 = blockIdx.x * 64, r0 = blockIdx.y * 64;
  const int t = threadIdx.x;
  const int rr = t >> 3, cb = (t & 7) * 8;
  const size_t base = (size_t)b * NNNN;
#pragma unroll
  for (int p = 0; p < 2; ++p) {
    const int r = rr + p * 32;
    const float* srow = src + base + (size_t)(r0 + r) * NN + c0 + cb;
    f32x4 v0 = *(const f32x4*)srow;
    f32x4 v1 = *(const f32x4*)(srow + 4);
    u16x8 w;
#pragma unroll
    for (int j = 0; j < 4; ++j) { w[j] = f2bf(v0[j]); w[4 + j] = f2bf(v1[j]); }
    *(u16x8*)(Wp + base + (size_t)(r0 + r) * NN + c0 + cb) = w;
#pragma unroll
    for (int j = 0; j < 4; ++j) { tile[r][cb + j] = v0[j]; tile[r][cb + 4 + j] = v1[j]; }
  }
  __syncthreads();
#pragma unroll
  for (int p = 0; p < 2; ++p) {
    const int r = rr + p * 32;
    u16x8 w;
#pragma unroll
    for (int j = 0; j < 8; ++j) w[j] = f2bf(tile[cb + j][r]);
    *(u16x8*)(WpT + base + (size_t)(c0 + r) * NN + r0 + cb) = w;
  }
}

__global__ __launch_bounds__(256) void convert_x(const float* __restrict__ x,
    unsigned short* __restrict__ xT) {
  __shared__ float tile[32][33];
  const int b = blockIdx.z;
  const int d0 = blockIdx.x * 32, n0 = blockIdx.y * 32;
  const int tx = threadIdx.x, ty = threadIdx.y;
#pragma unroll
  for (int s = 0; s < 4; ++s) {
    int rr = ty + s * 8;
    tile[rr][tx] = x[(size_t)b * NN * DD + (size_t)(n0 + rr) * DD + d0 + tx];
  }
  __syncthreads();
#pragma unroll
  for (int s = 0; s < 4; ++s) {
    int rr = ty + s * 8;
    xT[(size_t)b * DD * NN + (size_t)(d0 + rr) * NN + n0 + tx] = f2bf(tile[tx][rr]);
  }
}

// adj -> mcode bit0 (= adj[j,i]==1 at [i,j]), adj_bf, adjT_bf
__global__ __launch_bounds__(256) void mask0cvt(const float* __restrict__ adj,
    unsigned char* __restrict__ mcode, unsigned short* __restrict__ adjbf,
    unsigned short* __restrict__ adjTbf) {
  __shared__ float tile[32][33];
  const int i0 = blockIdx.x * 32, j0 = blockIdx.y * 32;
  const int tx = threadIdx.x, ty = threadIdx.y;
#pragma unroll
  for (int s = 0; s < 4; ++s) {
    int rr = ty + s * 8;
    float v = adj[(size_t)(j0 + rr) * NN + i0 + tx];
    adjbf[(size_t)(j0 + rr) * NN + i0 + tx] = f2bf(v);
    tile[rr][tx] = v;
  }
  __syncthreads();
#pragma unroll
  for (int s = 0; s < 4; ++s) {
    int rr = ty + s * 8;
    float v = tile[tx][rr];
    adjTbf[(size_t)(i0 + rr) * NN + j0 + tx] = f2bf(v);
    mcode[(size_t)(i0 + rr) * NN + j0 + tx] = (v == 1.0f) ? 1 : 0;
  }
}

// A2f f32 -> A2 bf16, A2T bf16, mcode bit1 at transposed idx where ==1
__global__ __launch_bounds__(256) void scan_a2(const float* __restrict__ A2f,
    unsigned short* __restrict__ A2, unsigned short* __restrict__ A2T,
    unsigned char* __restrict__ mcode) {
  __shared__ float tile[32][33];
  const int m0 = blockIdx.x * 32, n0 = blockIdx.y * 32;
  const int tx = threadIdx.x, ty = threadIdx.y;
#pragma unroll
  for (int s = 0; s < 4; ++s) {
    int rr = ty + s * 8;
    float v = A2f[(size_t)(m0 + rr) * NN + n0 + tx];
    A2[(size_t)(m0 + rr) * NN + n0 + tx] = f2bf(v);
    tile[rr][tx] = v;
  }
  __syncthreads();
#pragma unroll
  for (int s = 0; s < 4; ++s) {
    int rr = ty + s * 8;   // row of transposed tile (= source col n0+rr)
    float v = tile[tx][rr];
    A2T[(size_t)(n0 + rr) * NN + m0 + tx] = f2bf(v);
    if (v == 1.0f) mcode[(size_t)(n0 + rr) * NN + m0 + tx] |= 2;
  }
}

// A4f: record entries (m<<16)|n where ==1.0
__global__ __launch_bounds__(256) void scan_a4(const float* __restrict__ A4f,
    unsigned int* __restrict__ entries, int* __restrict__ nnz) {
  int e = blockIdx.x * 256 + threadIdx.x;
  float v = A4f[e];
  if (v == 1.0f) {
    int idx = atomicAdd(nnz, 1);
    if (idx < CAP) entries[idx] = ((unsigned)(e >> 10) << 16) | (unsigned)(e & 1023);
  }
}

// ---------------- register-prefetch pipelined MFMA GEMM ----------------
// C[m,n] = sum_k A[m,k]*B[n,k]. Double-buffered LDS, 1 raw barrier/iter,
// global->VGPR prefetch so the legalizer never vmcnt-blocks ds_reads.
#define BM 128
#define BN 128
#define BK 32

struct LoadPlain {
  const unsigned short* P;
  size_t stride;
  __device__ __forceinline__ u16x8 ld(int b, size_t off) const {
    return *(const u16x8*)(P + (size_t)b * stride + off);
  }
};

// A' = WcombT + (mcode&1 ? WpT : 0)   (hop0 fold during staging)
struct LoadComb {
  const unsigned short* Wc;
  const unsigned short* Wt;
  const unsigned char* mc;
  __device__ __forceinline__ u16x8 ld(int b, size_t off) const {
    size_t o = (size_t)b * NNNN + off;
    u16x8 a = *(const u16x8*)(Wc + o);
    u16x8 w = *(const u16x8*)(Wt + o);
    unsigned long long m = *(const unsigned long long*)(mc + off);
    u16x8 r;
#pragma unroll
    for (int j = 0; j < 8; ++j) {
      float s = bf2f(a[j]);
      if ((m >> (8 * j)) & 1ull) s += bf2f(w[j]);
      r[j] = f2bf(s);
    }
    return r;
  }
};

struct EpiWcomb {  // mask2-gated write (bf16 zero elsewhere)
  const unsigned char* mc;
  unsigned short* out;
  __device__ __forceinline__ void operator()(int b, int i, int j, float v) const {
    size_t idx = (size_t)i * NN + j;
    out[(size_t)b * NNNN + idx] = (mc[idx] & 2) ? f2bf(v) : (unsigned short)0;
  }
};

struct EpiAggAtom {
  float* agg;
  __device__ __forceinline__ void operator()(int b, int i, int d, float v) const {
    atomicAdd(agg + (size_t)b * NN * DD + (size_t)i * DD + d, v);
  }
};

struct EpiSqAtom {
  float* buf;
  __device__ __forceinline__ void operator()(int b, int m, int n, float v) const {
    atomicAdd(buf + (size_t)m * NN + n, v);
  }
};

#define LGKM_BARRIER() do { \
  asm volatile("s_waitcnt lgkmcnt(0)" ::: "memory"); \
  __builtin_amdgcn_s_barrier(); \
  asm volatile("" ::: "memory"); } while (0)

template <typename LA, typename Epi>
__global__ __launch_bounds__(256, 3) void gemm_pipe(LA la, LoadPlain lb,
    int swz, int ksN, int nit, Epi epi) {
  __shared__ __align__(16) unsigned short As[2 * BM * BK];
  __shared__ __align__(16) unsigned short Bs[2 * BN * BK];
  const int z = blockIdx.z;
  const int b = z / ksN, ks = z - b * ksN;
  const int kbase = ks * nit * BK;
  int bx = blockIdx.x, by = blockIdx.y;
  if (swz) {  // 2x4 rect for per-XCD L2 locality
    int lin = bx + (by << 3);
    int r = lin & 7, s = lin >> 3;
    bx = ((r & 3) << 1) | (s & 1);
    by = ((r >> 2) << 2) | (s >> 1);
  }
  const int tm = bx * BM, tn = by * BN;
  const int tid = threadIdx.x;
  const int w = tid >> 6, l = tid & 63;
  const int lr = l >> 2, lc = l & 3;
  const int fr = l & 15, quad = l >> 4;
  const int moff = (w & 1) * 64, noff = (w >> 1) * 64;

  // staging geometry: two 16-row groups per wave; XOR swizzle on k-chunk
  const int r0 = w * 16 + lr, r1 = (w + 4) * 16 + lr;
  const int kc0 = lc ^ ((r0 >> 1) & 3), kc1 = lc ^ ((r1 >> 1) & 3);
  const size_t aoff0 = (size_t)(tm + r0) * NN + kbase + kc0 * 8;
  const size_t aoff1 = (size_t)(tm + r1) * NN + kbase + kc1 * 8;
  const size_t boff0 = (size_t)(tn + r0) * NN + kbase + kc0 * 8;
  const size_t boff1 = (size_t)(tn + r1) * NN + kbase + kc1 * 8;
  // LDS slots use raw lc (global chunk kc sits at slot kc^swz == lc)
  const int lsA0 = r0 * BK + lc * 8, lsA1 = r1 * BK + lc * 8;

  f32x4 acc[4][4];
#pragma unroll
  for (int mi = 0; mi < 4; ++mi)
#pragma unroll
    for (int ni = 0; ni < 4; ++ni) acc[mi][ni] = (f32x4){0.f, 0.f, 0.f, 0.f};

  u16x8 va0, va1, vb0, vb1;
  auto load_tile = [&](int kt) {
    size_t kk = (size_t)kt * BK;
    va0 = la.ld(b, aoff0 + kk); va1 = la.ld(b, aoff1 + kk);
    vb0 = lb.ld(b, boff0 + kk); vb1 = lb.ld(b, boff1 + kk);
  };
  auto write_tile = [&](int par) {
    unsigned short* Ad = As + par * (BM * BK);
    unsigned short* Bd = Bs + par * (BN * BK);
    *(u16x8*)(Ad + lsA0) = va0; *(u16x8*)(Ad + lsA1) = va1;
    *(u16x8*)(Bd + lsA0) = vb0; *(u16x8*)(Bd + lsA1) = vb1;
  };
  auto compute = [&](int par) {
    const unsigned short* Ab = As + par * (BM * BK);
    const unsigned short* Bb = Bs + par * (BN * BK);
    bf16x8 af[4], bfr[4];
#pragma unroll
    for (int mi = 0; mi < 4; ++mi) {
      int r = moff + mi * 16 + fr;
      int kc = quad ^ ((r >> 1) & 3);
      af[mi] = *(const bf16x8*)(Ab + r * BK + kc * 8);
    }
#pragma unroll
    for (int ni = 0; ni < 4; ++ni) {
      int r = noff + ni * 16 + fr;
      int kc = quad ^ ((r >> 1) & 3);
      bfr[ni] = *(const bf16x8*)(Bb + r * BK + kc * 8);
    }
#pragma unroll
    for (int mi = 0; mi < 4; ++mi)
#pragma unroll
      for (int ni = 0; ni < 4; ++ni)
        acc[mi][ni] = __builtin_amdgcn_mfma_f32_16x16x32_bf16(af[mi], bfr[ni], acc[mi][ni], 0, 0, 0);
  };

  // prologue
  load_tile(0);
  write_tile(0);
  load_tile(1);
  LGKM_BARRIER();
#pragma unroll 1
  for (int kt = 0; kt < nit - 2; ++kt) {
    compute(kt & 1);
    write_tile((kt + 1) & 1);   // vmcnt wait covers load_tile(kt+1) (1 iter old)
    load_tile(kt + 2);
    LGKM_BARRIER();
  }
  compute((nit - 2) & 1);
  write_tile((nit - 1) & 1);
  LGKM_BARRIER();
  compute((nit - 1) & 1);

  // C/D layout: col = lane&15, row = quad*4 + reg
#pragma unroll
  for (int mi = 0; mi < 4; ++mi)
#pragma unroll
    for (int ni = 0; ni < 4; ++ni)
#pragma unroll
      for (int t = 0; t < 4; ++t)
        epi(b, tm + moff + mi * 16 + quad * 4 + t, tn + noff + ni * 16 + fr, acc[mi][ni][t]);
}

// ---------------- gated hop-2 sparse fixup (expected: nnz==0, exits) ----------------
__global__ __launch_bounds__(256) void hop2_fix(const unsigned short* __restrict__ Wp,
    const unsigned short* __restrict__ WpT, const int* __restrict__ nnz,
    const unsigned int* __restrict__ entries, unsigned short* __restrict__ WcombT) {
  int n = *nnz;
  if (n > CAP) n = CAP;
  if (n == 0) return;
  __shared__ float rbuf[256];
  const int b = blockIdx.x;
  const size_t bnn = (size_t)b * NNNN;
  for (int e = blockIdx.y; e < n; e += gridDim.y) {
    unsigned int ent = entries[e];
    int j = ent >> 16, i = ent & 0xFFFF;
    float s = 0.f;
    for (int k = threadIdx.x; k < NN; k += 256) {
      float u = 0.f, v = 0.f;
      const unsigned short* wj  = Wp  + bnn + (size_t)j * NN;
      const unsigned short* wtk = WpT + bnn + (size_t)k * NN;
      const unsigned short* wk  = Wp  + bnn + (size_t)k * NN;
      const unsigned short* wti = WpT + bnn + (size_t)i * NN;
      for (int t = 0; t < NN; ++t) {
        u += bf2f(wj[t]) * bf2f(wtk[t]);
        v += bf2f(wk[t]) * bf2f(wti[t]);
      }
      s += u * v;
    }
    rbuf[threadIdx.x] = s;
    __syncthreads();
    for (int off = 128; off > 0; off >>= 1) {
      if (threadIdx.x < off) rbuf[threadIdx.x] += rbuf[threadIdx.x + off];
      __syncthreads();
    }
    if (threadIdx.x == 0) {
      size_t idx = bnn + (size_t)i * NN + j;
      WcombT[idx] = f2bf(bf2f(WcombT[idx]) + rbuf[0]);
    }
    __syncthreads();
  }
}

// ---------------- fused Linear + residual + LayerNorm ----------------
#define ROWS_PER_BLK 32
__global__ __launch_bounds__(256) void fused_out(const float* agg, const float* __restrict__ x,
    const float* __restrict__ W, const float* __restrict__ bias,
    const float* __restrict__ g2, const float* __restrict__ bsh, float* out) {
  __shared__ unsigned short Wl[128 * 136];
  __shared__ float ar[256];
  __shared__ float xr[256];
  __shared__ float wred[8];
  const int tid = threadIdx.x;
  for (int e = tid; e < 16384; e += 256) Wl[(e >> 7) * 136 + (e & 127)] = f2bf(W[e]);
  const int half = tid >> 7, o = tid & 127;
  const int w = tid >> 6, lane = tid & 63;
  const float bo = bias[o], go = g2[o], b2o = bsh[o];
  const size_t row0 = (size_t)blockIdx.x * ROWS_PER_BLK;
  for (int rr = 0; rr < ROWS_PER_BLK; rr += 2) {
    const size_t rbase = (row0 + rr) * DD;
    __syncthreads();
    ar[tid] = agg[rbase + tid];
    xr[tid] = x[rbase + tid];
    __syncthreads();
    float hv = bo + xr[half * 128 + o];
    const unsigned short* wrow = &Wl[o * 136];
    const float* arow = &ar[half * 128];
#pragma unroll
    for (int d8 = 0; d8 < 16; ++d8) {
      bf16x8 wv = *(const bf16x8*)(wrow + d8 * 8);
#pragma unroll
      for (int t = 0; t < 8; ++t) hv += (float)wv[t] * arow[d8 * 8 + t];
    }
    float s = hv, q = hv * hv;
#pragma unroll
    for (int off = 32; off > 0; off >>= 1) {
      s += __shfl_xor(s, off);
      q += __shfl_xor(q, off);
    }
    if (lane == 0) { wred[w] = s; wred[4 + w] = q; }
    __syncthreads();
    float st = wred[half * 2] + wred[half * 2 + 1];
    float qt = wred[4 + half * 2] + wred[4 + half * 2 + 1];
    float mean = st * (1.0f / 128.0f);
    float var = (qt - 128.0f * mean * mean) * (1.0f / 127.0f);
    var = fmaxf(var, 0.0f);
    float stdv = sqrtf(var);
    out[rbase + tid] = go * (hv - mean) / (stdv + EPSF) + b2o;
  }
}

// ---------------- launch ----------------
extern "C" void kernel_launch(void* const* d_in, const int* in_sizes, int n_in,
                              void* d_out, int out_size, void* d_ws, size_t ws_size,
                              hipStream_t stream) {
  (void)in_sizes; (void)n_in; (void)out_size; (void)ws_size;
  const float* x    = (const float*)d_in[0];
  const float* adjw = (const float*)d_in[1];
  const float* adj  = (const float*)d_in[2];
  const float* W    = (const float*)d_in[3];
  const float* bias = (const float*)d_in[4];
  const float* a2   = (const float*)d_in[5];
  const float* b2   = (const float*)d_in[6];
  float* out = (float*)d_out;

  char* ws = (char*)d_ws;
  unsigned short* Wp_bf   = (unsigned short*)(ws);                 // 64 MiB
  unsigned short* WpT_bf  = (unsigned short*)(ws + 67108864);      // 64 MiB
  unsigned short* WcombT  = (unsigned short*)(ws + 134217728);     // 64 MiB
  unsigned short* xT_bf   = (unsigned short*)(ws + 201326592);     // 8 MiB
  unsigned short* adj_bf  = (unsigned short*)(ws + 209715200);     // 2 MiB
  unsigned short* adjT_bf = (unsigned short*)(ws + 211812352);     // 2 MiB
  unsigned short* A2_bf   = (unsigned short*)(ws + 213909504);     // 2 MiB
  unsigned short* A2T_bf  = (unsigned short*)(ws + 216006656);     // 2 MiB
  float* A2f              = (float*)(ws + 218103808);              // 4 MiB
  float* A4f              = (float*)(ws + 222298112);              // 4 MiB
  unsigned char* mcode    = (unsigned char*)(ws + 226492416);      // 1 MiB
  unsigned int* entries   = (unsigned int*)(ws + 227540992);       // 64 KiB
  int* nnz2               = (int*)(ws + 227606528);                // 4 B
  float* agg = out;  // d_out doubles as f32 accumulation target

  hipMemsetAsync(nnz2, 0, 4, stream);
  hipMemsetAsync(A2f, 0, (size_t)4 * NNNN, stream);
  hipMemsetAsync(A4f, 0, (size_t)4 * NNNN, stream);
  hipMemsetAsync(agg, 0, (size_t)BB * NN * DD * 4, stream);

  dim3 blk32(32, 8, 1);
  convert_wp<<<dim3(16, 16, 32), 256, 0, stream>>>(adjw, Wp_bf, WpT_bf);
  convert_x<<<dim3(4, 32, 32), blk32, 0, stream>>>(x, xT_bf);
  mask0cvt<<<dim3(32, 32, 1), blk32, 0, stream>>>(adj, mcode, adj_bf, adjT_bf);

  // A^2: K-split 4, exact integer partials via f32 atomics
  gemm_pipe<<<dim3(8, 8, 4), 256, 0, stream>>>(
      LoadPlain{adj_bf, 0}, LoadPlain{adjT_bf, 0}, 0, 4, NN / 4 / BK, EpiSqAtom{A2f});
  scan_a2<<<dim3(32, 32, 1), blk32, 0, stream>>>(A2f, A2_bf, A2T_bf, mcode);
  // A^4: K-split 4 (A^2 ints < 256 exact in bf16)
  gemm_pipe<<<dim3(8, 8, 4), 256, 0, stream>>>(
      LoadPlain{A2_bf, 0}, LoadPlain{A2T_bf, 0}, 0, 4, NN / 4 / BK, EpiSqAtom{A4f});
  scan_a4<<<dim3(4096, 1, 1), 256, 0, stream>>>(A4f, entries, nnz2);

  // big batched gemm: WcombT = mask2 .* (Wp^2)^T
  gemm_pipe<<<dim3(8, 8, 32), 256, 0, stream>>>(
      LoadPlain{WpT_bf, NNNN}, LoadPlain{Wp_bf, NNNN}, 1, 1, NN / BK,
      EpiWcomb{mcode, WcombT});

  hop2_fix<<<dim3(32, 8, 1), 256, 0, stream>>>(Wp_bf, WpT_bf, nnz2, entries, WcombT);

  // agg = (WcombT + mask1^T.*WpT) @ x   — K-split 2, f32 atomic accumulate
  gemm_pipe<<<dim3(8, 1, 64), 256, 0, stream>>>(
      LoadComb{WcombT, WpT_bf, mcode}, LoadPlain{xT_bf, (size_t)DD * NN}, 0, 2,
      NN / 2 / BK, EpiAggAtom{agg});

  fused_out<<<dim3(1024, 1, 1), 256, 0, stream>>>(agg, x, W, bias, a2, b2, out);
}